// Round 9
// baseline (113.319 us; speedup 1.0000x reference)
//
#include <hip/hip_runtime.h>
#include <hip/hip_fp16.h>

#define DIM_IN 128
#define DIM_HID 64
#define BK_SHIFT 9
#define BK_SIZE 512            // nodes per coarse bucket
#define SRC_BITS 17            // n = 100000 < 2^17
#define CAP 6144               // part capacity/bucket (E[edges]=5120, sigma~72)
#define CAP2 8192              // padded srcs capacity/bucket (<= 6144 + 3*512)
#define P_EPT  16
#define P_TILE 4096

typedef _Float16 half8 __attribute__((ext_vector_type(8)));
typedef float floatx4 __attribute__((ext_vector_type(4)));

// ---------------- tiny init: bcur = 0, dinv[n] = 0, h2 sentinel row = 0 ----------------

__global__ void zero_kernel(int* __restrict__ bcur, float* __restrict__ dinv_sent,
                            int* __restrict__ h2row_n) {
    bcur[threadIdx.x] = 0;
    if (threadIdx.x == 0) dinv_sent[0] = 0.0f;     // dinv[n]: sentinel norm
    if (threadIdx.x < 32) h2row_n[threadIdx.x] = 0; // h2 row n (128B) = 0
}

// ---------------- fused A: blocks [0,gb) gemm1 | blocks [gb,gb+pb) partition ----------------
// gemm1: h = fp16(x @ W1), raw (no dinv), rows >= n zeroed (sentinel).
// partition: pack = (dst&511)<<17 | src into per-bucket runs at bid*CAP + cursor.

__global__ __launch_bounds__(256)
void gemm1_partition_kernel(const float* __restrict__ x, const float* __restrict__ W,
                            _Float16* __restrict__ h, int n, int gb,
                            const int* __restrict__ src, const int* __restrict__ dst,
                            int* __restrict__ bcur, int* __restrict__ part, int E) {
    __shared__ int smem[5888];                    // 23552 B: max(gemm 17408, part 23552)
    const int tid = threadIdx.x;

    if (blockIdx.x < gb) {
        // ------------ gemm1 (K=128) ------------
        constexpr int K = DIM_IN, LDK = K + 8;
        _Float16* Wt = (_Float16*)smem;
        for (int idx = tid; idx < K * 64; idx += 256) {   // W[k][c] -> Wt[c][k] fp16
            int k = idx >> 6, c = idx & 63;
            Wt[c * LDK + k] = (_Float16)W[idx];
        }
        __syncthreads();

        const int wave = tid >> 6;
        const int lane = tid & 63;
        const int r    = lane & 15;
        const int g    = lane >> 4;
        const int row0 = blockIdx.x * 64 + wave * 16;
        const int arow = row0 + r;
        const float* xrow = x + (size_t)(arow < n ? arow : 0) * K + g * 8;

        floatx4 acc0 = {}, acc1 = {}, acc2 = {}, acc3 = {};
#pragma unroll
        for (int kt = 0; kt < K / 32; ++kt) {
            float4 a0 = *(const float4*)(xrow + kt * 32);
            float4 a1 = *(const float4*)(xrow + kt * 32 + 4);
            half8 a;
            a[0] = (_Float16)a0.x; a[1] = (_Float16)a0.y;
            a[2] = (_Float16)a0.z; a[3] = (_Float16)a0.w;
            a[4] = (_Float16)a1.x; a[5] = (_Float16)a1.y;
            a[6] = (_Float16)a1.z; a[7] = (_Float16)a1.w;

            const _Float16* wb = &Wt[r * LDK + kt * 32 + g * 8];
            half8 b0 = *(const half8*)(wb + 0 * 16 * LDK);
            half8 b1 = *(const half8*)(wb + 1 * 16 * LDK);
            half8 b2 = *(const half8*)(wb + 2 * 16 * LDK);
            half8 b3 = *(const half8*)(wb + 3 * 16 * LDK);
            acc0 = __builtin_amdgcn_mfma_f32_16x16x32_f16(a, b0, acc0, 0, 0, 0);
            acc1 = __builtin_amdgcn_mfma_f32_16x16x32_f16(a, b1, acc1, 0, 0, 0);
            acc2 = __builtin_amdgcn_mfma_f32_16x16x32_f16(a, b2, acc2, 0, 0, 0);
            acc3 = __builtin_amdgcn_mfma_f32_16x16x32_f16(a, b3, acc3, 0, 0, 0);
        }

        // D: col = lane&15 (=r), row = g*4 + j   [m89-verified]
#pragma unroll
        for (int j = 0; j < 4; ++j) {
            int drow = row0 + g * 4 + j;
            _Float16* o = h + (size_t)drow * 64 + r;
            if (drow < n) {
                o[0]  = (_Float16)acc0[j];
                o[16] = (_Float16)acc1[j];
                o[32] = (_Float16)acc2[j];
                o[48] = (_Float16)acc3[j];
            } else {                                   // sentinel zero rows [n, gb*64)
                o[0] = (_Float16)0; o[16] = (_Float16)0;
                o[32] = (_Float16)0; o[48] = (_Float16)0;
            }
        }
    } else {
        // ------------ partition ------------
        int* hist  = smem;
        int* bofs  = smem + 256;
        int* gbase = smem + 512;
        int* stage = smem + 768;                       // 4096 ints
        unsigned char* auxb = (unsigned char*)(smem + 4864);  // 4096 B
        const int tile0 = (blockIdx.x - gb) * P_TILE;
        const int tcnt  = min(P_TILE, E - tile0);

        hist[tid] = 0;
        __syncthreads();

        int pack[P_EPT], bb[P_EPT], lo[P_EPT];
#pragma unroll
        for (int i = 0; i < P_EPT; ++i) {
            int e = tile0 + i * 256 + tid;
            bb[i] = -1;
            if (e < E) {
                int d = dst[e];
                int s = src[e];
                bb[i]   = d >> BK_SHIFT;
                pack[i] = ((d & (BK_SIZE - 1)) << SRC_BITS) | s;
                lo[i]   = atomicAdd(&hist[bb[i]], 1);
            }
        }
        __syncthreads();

        bofs[tid] = hist[tid];
        __syncthreads();
        for (int off = 1; off < 256; off <<= 1) {
            int t = (tid >= off) ? bofs[tid - off] : 0;
            __syncthreads();
            bofs[tid] += t;
            __syncthreads();
        }
        int ex = bofs[tid] - hist[tid];
        __syncthreads();
        bofs[tid] = ex;                                // exclusive, for lookups
        if (hist[tid]) gbase[tid] = tid * CAP + atomicAdd(&bcur[tid], hist[tid]);
        __syncthreads();

#pragma unroll
        for (int i = 0; i < P_EPT; ++i) {
            if (bb[i] >= 0) {
                int p = bofs[bb[i]] + lo[i];
                stage[p] = pack[i];
                auxb[p]  = (unsigned char)bb[i];
            }
        }
        __syncthreads();

        for (int k = tid; k < tcnt; k += 256) {        // contiguous runs per bucket
            int b = auxb[k];
            part[gbase[b] + (k - bofs[b])] = stage[k];
        }
    }
}

// ---------------- per-bucket local fill + degree-sorted order ----------------
// Edge lists padded to x4 with sentinel ZROW=n. order[] = bucket's nodes
// counting-sorted by padded degree -> gather waves get uniform trip counts.

__global__ __launch_bounds__(256)
void bucket_fill_kernel(const int* __restrict__ bcur, const int* __restrict__ part,
                        int2* __restrict__ nodeinfo, float* __restrict__ dinv,
                        int* __restrict__ srcs, int* __restrict__ order,
                        int n, int zrow) {
    __shared__ int cnt[BK_SIZE];
    __shared__ int rp[BK_SIZE];
    __shared__ int s2[256];
    __shared__ int hist2[32];
    __shared__ int total;
    const int tid   = threadIdx.x;
    const int bid   = blockIdx.x;
    const int node0 = bid << BK_SHIFT;
    const int bs    = min(BK_SIZE, n - node0);
    const int pbase = bid * CAP;
    const int sbase = bid * CAP2;
    const int ecnt  = bcur[bid];

    cnt[tid] = 0; cnt[tid + 256] = 0;
    if (tid < 32) hist2[tid] = 0;
    __syncthreads();
    for (int k = tid; k < ecnt; k += 256)
        atomicAdd(&cnt[part[pbase + k] >> SRC_BITS], 1);
    __syncthreads();

    int c0 = cnt[2 * tid], c1 = cnt[2 * tid + 1];
    int p0 = (c0 + 3) & ~3, p1 = (c1 + 3) & ~3;           // padded counts
    s2[tid] = p0 + p1;
    __syncthreads();
    for (int off = 1; off < 256; off <<= 1) {
        int t = (tid >= off) ? s2[tid - off] : 0;
        __syncthreads();
        s2[tid] += t;
        __syncthreads();
    }
    int ex = s2[tid] - (p0 + p1);
    rp[2 * tid]     = ex;
    rp[2 * tid + 1] = ex + p0;
    if (tid == 255) total = s2[255];
    __syncthreads();

    for (int i = tid; i < bs; i += 256) {                  // coalesced
        int c = cnt[i];
        nodeinfo[node0 + i] = make_int2(sbase + rp[i], (c + 3) & ~3);
        dinv[node0 + i]     = rsqrtf((float)c + 1.0f);     // +1 self-loop
        atomicAdd(&hist2[min((c + 3) >> 2, 31)], 1);       // degree histogram
    }
    __syncthreads();

    if (tid == 0) {                                        // exclusive scan, 32 bins
        int run = 0;
        for (int b = 0; b < 32; ++b) { int t = hist2[b]; hist2[b] = run; run += t; }
    }
    __syncthreads();
    for (int i = tid; i < bs; i += 256) {                  // counting-sort scatter
        int k = min((cnt[i] + 3) >> 2, 31);
        int pos = atomicAdd(&hist2[k], 1);
        order[node0 + pos] = node0 + i;
    }
    __syncthreads();

    cnt[tid] = 0; cnt[tid + 256] = 0;                      // reuse as cursors
    __syncthreads();
    for (int k = tid; k < total; k += 256) srcs[sbase + k] = zrow;  // pad fill
    __syncthreads();
    for (int k = tid; k < ecnt; k += 256) {
        int v    = part[pbase + k];
        int li   = v >> SRC_BITS;
        int slot = atomicAdd(&cnt[li], 1);
        srcs[sbase + rp[li] + slot] = v & ((1 << SRC_BITS) - 1);  // L2-local window
    }
}

// ---------------- fused B: gather layer-1 + relu into LDS tile, then MFMA with W2 ----------------
// 64 nodes/block IN DEGREE-SORTED ORDER. h2 written PRE-SCALED by dinv[node]
// (scatter-store by order). Rows >= n never written (h2[n] zeroed by zero_kernel).

__global__ __launch_bounds__(256)
void layer2_fused_kernel(const int2* __restrict__ nodeinfo, const int* __restrict__ srcs,
                         const float* __restrict__ dinv, const int* __restrict__ order,
                         const half8* __restrict__ hs, const float* __restrict__ b1,
                         const float* __restrict__ W2, _Float16* __restrict__ h2, int n) {
    __shared__ _Float16 At[64 * 72];
    __shared__ _Float16 Wt[64 * 72];
    const int tid = threadIdx.x;

    for (int idx = tid; idx < 64 * 64; idx += 256) {   // W2[k][c] -> Wt[c][k] fp16
        int k = idx >> 6, c = idx & 63;
        Wt[c * 72 + k] = (_Float16)W2[idx];
    }

    const int f    = tid & 7;
    const int grp  = tid >> 3;
    const int row0 = blockIdx.x * 64;

#pragma unroll
    for (int rnd = 0; rnd < 2; ++rnd) {
        const int nrow = rnd * 32 + grp;
        half8 o = {};
        if (row0 + nrow < n) {
            const int node = order[row0 + nrow];
            int2 info = nodeinfo[node];
            int start = info.x, cpad = info.y;
            float dn = dinv[node];
            half8 sv = hs[(size_t)node * 8 + f];       // self-loop term
            float acc[8];
#pragma unroll
            for (int i = 0; i < 8; ++i) acc[i] = dn * (float)sv[i];

            for (int j = 0; j < cpad; j += 4) {
                int4 ss = *(const int4*)&srcs[start + j];
                float d0 = dinv[ss.x], d1 = dinv[ss.y], d2 = dinv[ss.z], d3 = dinv[ss.w];
                half8 v0 = hs[(size_t)ss.x * 8 + f];
                half8 v1 = hs[(size_t)ss.y * 8 + f];
                half8 v2 = hs[(size_t)ss.z * 8 + f];
                half8 v3 = hs[(size_t)ss.w * 8 + f];
#pragma unroll
                for (int i = 0; i < 8; ++i)
                    acc[i] += (d0 * (float)v0[i] + d1 * (float)v1[i]) +
                              (d2 * (float)v2[i] + d3 * (float)v3[i]);
            }
#pragma unroll
            for (int i = 0; i < 8; ++i) {
                float g1 = fmaf(acc[i], dn, b1[f * 8 + i]);
                o[i] = (_Float16)fmaxf(g1, 0.0f);      // relu
            }
        }
        *(half8*)&At[nrow * 72 + f * 8] = o;
    }
    __syncthreads();

    // MFMA phase: wave w -> 16 output rows (sorted-local), K=64
    const int wave = tid >> 6;
    const int lane = tid & 63;
    const int r    = lane & 15;
    const int g    = lane >> 4;

    floatx4 acc0 = {}, acc1 = {}, acc2 = {}, acc3 = {};
#pragma unroll
    for (int kt = 0; kt < 2; ++kt) {
        half8 a = *(const half8*)&At[(wave * 16 + r) * 72 + kt * 32 + g * 8];
        const _Float16* wb = &Wt[r * 72 + kt * 32 + g * 8];
        half8 b0 = *(const half8*)(wb + 0 * 16 * 72);
        half8 b1v = *(const half8*)(wb + 1 * 16 * 72);
        half8 b2v = *(const half8*)(wb + 2 * 16 * 72);
        half8 b3v = *(const half8*)(wb + 3 * 16 * 72);
        acc0 = __builtin_amdgcn_mfma_f32_16x16x32_f16(a, b0, acc0, 0, 0, 0);
        acc1 = __builtin_amdgcn_mfma_f32_16x16x32_f16(a, b1v, acc1, 0, 0, 0);
        acc2 = __builtin_amdgcn_mfma_f32_16x16x32_f16(a, b2v, acc2, 0, 0, 0);
        acc3 = __builtin_amdgcn_mfma_f32_16x16x32_f16(a, b3v, acc3, 0, 0, 0);
    }

    // D: col = r, local row = wave*16 + g*4 + j; store PRE-SCALED to h2[order[...]]
#pragma unroll
    for (int j = 0; j < 4; ++j) {
        int rl = row0 + wave * 16 + g * 4 + j;
        if (rl < n) {
            int node2 = order[rl];
            float dn2 = dinv[node2];
            _Float16* o = h2 + (size_t)node2 * 64 + r;
            o[0]  = (_Float16)(acc0[j] * dn2);
            o[16] = (_Float16)(acc1[j] * dn2);
            o[32] = (_Float16)(acc2[j] * dn2);
            o[48] = (_Float16)(acc3[j] * dn2);
        }
    }
}

// ---------------- final gather: out[d] = dinv[d]*(sum h2[s] + h2[d]) + b2 ----------------
// h2 pre-scaled by dinv -> no per-edge dinv loads. Degree-sorted processing.

__global__ __launch_bounds__(256)
void gather_out_kernel(const int2* __restrict__ nodeinfo, const int* __restrict__ srcs,
                       const float* __restrict__ dinv, const int* __restrict__ order,
                       const half8* __restrict__ hs, const float* __restrict__ b,
                       float* __restrict__ out, int n) {
    const int tid  = threadIdx.x;
    const int f    = tid & 7;
    const int gidx = blockIdx.x * 32 + (tid >> 3);
    if (gidx >= n) return;
    const int node = order[gidx];

    int2 info = nodeinfo[node];
    int start = info.x, cpad = info.y;

    half8 sv = hs[(size_t)node * 8 + f];   // self term (pre-scaled)
    float acc[8];
#pragma unroll
    for (int i = 0; i < 8; ++i) acc[i] = (float)sv[i];

    for (int j = 0; j < cpad; j += 4) {
        int4 ss = *(const int4*)&srcs[start + j];
        half8 v0 = hs[(size_t)ss.x * 8 + f];
        half8 v1 = hs[(size_t)ss.y * 8 + f];
        half8 v2 = hs[(size_t)ss.z * 8 + f];
        half8 v3 = hs[(size_t)ss.w * 8 + f];
#pragma unroll
        for (int i = 0; i < 8; ++i)
            acc[i] += ((float)v0[i] + (float)v1[i]) + ((float)v2[i] + (float)v3[i]);
    }

    float dn = dinv[node];
    const float4* b4 = (const float4*)b;
    float4 bb0 = b4[f * 2], bb1 = b4[f * 2 + 1];
    float4 o0 = make_float4(fmaf(acc[0], dn, bb0.x), fmaf(acc[1], dn, bb0.y),
                            fmaf(acc[2], dn, bb0.z), fmaf(acc[3], dn, bb0.w));
    float4 o1 = make_float4(fmaf(acc[4], dn, bb1.x), fmaf(acc[5], dn, bb1.y),
                            fmaf(acc[6], dn, bb1.z), fmaf(acc[7], dn, bb1.w));
    float4* o4 = (float4*)out;
    o4[(size_t)node * 16 + f * 2]     = o0;
    o4[(size_t)node * 16 + f * 2 + 1] = o1;
}

// ---------------- launch ----------------

extern "C" void kernel_launch(void* const* d_in, const int* in_sizes, int n_in,
                              void* d_out, int out_size, void* d_ws, size_t ws_size,
                              hipStream_t stream) {
    const float* x   = (const float*)d_in[0];
    const int*   ei  = (const int*)d_in[1];   // int64 demoted to int32 by JAX default config
    const float* W1  = (const float*)d_in[2];
    const float* b1  = (const float*)d_in[3];
    const float* W2  = (const float*)d_in[4];
    const float* b2  = (const float*)d_in[5];
    float*       out = (float*)d_out;

    const int n = in_sizes[0] / DIM_IN;   // 100000
    const int E = in_sizes[1] / 2;        // 1000000
    const int* srcp = ei;
    const int* dstp = ei + E;
    const int NB    = (n + BK_SIZE - 1) >> BK_SHIFT;   // 196
    const int gb    = (n + 63) / 64;                   // 1563
    const int pb    = (E + P_TILE - 1) / P_TILE;       // 245
    const int ab    = (n + 31) / 32;
    const size_t nrows = (size_t)gb * 64;              // h rows incl. zero sentinels

    const int npad = ((n + 255) / 256) * 256;

    // workspace layout (4B words):
    int*      bcur     = (int*)d_ws;                          // 256
    int2*     nodeinfo = (int2*)(bcur + 256);                 // 2*npad words
    float*    dinv     = (float*)((int*)nodeinfo + 2 * npad); // npad (incl. dinv[n] sentinel)
    int*      order    = (int*)(dinv + npad);                 // npad
    int*      srcs     = order + npad;                        // NB*CAP2
    int*      part     = srcs + (size_t)NB * CAP2;            // NB*CAP
    _Float16* h        = (_Float16*)(part + (size_t)NB * CAP); // nrows*64 halves
    _Float16* h2       = h + nrows * 64;                      // (n+1)*64 halves (row n = sentinel)

    // 1) init cursors + sentinels
    zero_kernel<<<1, 256, 0, stream>>>(bcur, &dinv[n], (int*)(h2 + (size_t)n * 64));
    // 2) gemm1 (h = fp16(x@W1), raw) overlapped with edge partition
    gemm1_partition_kernel<<<gb + pb, 256, 0, stream>>>(x, W1, h, n, gb,
                                                        srcp, dstp, bcur, part, E);
    // 3) per-bucket CSR fill (nodeinfo, dinv, padded srcs, degree-sorted order)
    bucket_fill_kernel<<<NB, 256, 0, stream>>>(bcur, part, nodeinfo, dinv, srcs, order, n, n);
    // 4) layer1 gather + relu + layer2 GEMM fused -> h2 (pre-scaled by dinv)
    layer2_fused_kernel<<<gb, 256, 0, stream>>>(nodeinfo, srcs, dinv, order, (const half8*)h,
                                                b1, W2, h2, n);
    // 5) layer2 gather -> out (fp32)
    gather_out_kernel<<<ab, 256, 0, stream>>>(nodeinfo, srcs, dinv, order, (const half8*)h2,
                                              b2, out, n);
}

// Round 10
// 102.115 us; speedup vs baseline: 1.1097x; 1.1097x over previous
//
#include <hip/hip_runtime.h>
#include <hip/hip_fp16.h>

#define DIM_IN 128
#define DIM_HID 64
#define BK_SHIFT 9
#define BK_SIZE 512            // nodes per coarse bucket
#define SRC_BITS 17            // n = 100000 < 2^17
#define CAP 6144               // part capacity/bucket (E[edges]=5120, sigma~72)
#define CAP2 8192              // padded srcs capacity/bucket (<= 6144 + 3*512)
#define P_EPT  16
#define P_TILE 4096

typedef _Float16 half8 __attribute__((ext_vector_type(8)));
typedef float floatx4 __attribute__((ext_vector_type(4)));

// ---------------- tiny init: bcur = 0, dinv[n] = 0 (sentinel) ----------------

__global__ void zero_kernel(int* __restrict__ bcur, float* __restrict__ dinv_sent) {
    bcur[threadIdx.x] = 0;
    if (threadIdx.x == 0) dinv_sent[0] = 0.0f;     // dinv[n]: sentinel norm
}

// ---------------- fused A: blocks [0,gb) gemm1 | blocks [gb,gb+pb) partition ----------------
// gemm1: h = fp16(x @ W1), raw (no dinv), rows >= n zeroed (sentinel).
// partition: pack = (dst&511)<<17 | src into per-bucket runs at bid*CAP + cursor.

__global__ __launch_bounds__(256)
void gemm1_partition_kernel(const float* __restrict__ x, const float* __restrict__ W,
                            _Float16* __restrict__ h, int n, int gb,
                            const int* __restrict__ src, const int* __restrict__ dst,
                            int* __restrict__ bcur, int* __restrict__ part, int E) {
    __shared__ int smem[5888];                    // 23552 B: max(gemm 17408, part 23552)
    const int tid = threadIdx.x;

    if (blockIdx.x < gb) {
        // ------------ gemm1 (K=128) ------------
        constexpr int K = DIM_IN, LDK = K + 8;
        _Float16* Wt = (_Float16*)smem;
        for (int idx = tid; idx < K * 64; idx += 256) {   // W[k][c] -> Wt[c][k] fp16
            int k = idx >> 6, c = idx & 63;
            Wt[c * LDK + k] = (_Float16)W[idx];
        }
        __syncthreads();

        const int wave = tid >> 6;
        const int lane = tid & 63;
        const int r    = lane & 15;
        const int g    = lane >> 4;
        const int row0 = blockIdx.x * 64 + wave * 16;
        const int arow = row0 + r;
        const float* xrow = x + (size_t)(arow < n ? arow : 0) * K + g * 8;

        floatx4 acc0 = {}, acc1 = {}, acc2 = {}, acc3 = {};
#pragma unroll
        for (int kt = 0; kt < K / 32; ++kt) {
            float4 a0 = *(const float4*)(xrow + kt * 32);
            float4 a1 = *(const float4*)(xrow + kt * 32 + 4);
            half8 a;
            a[0] = (_Float16)a0.x; a[1] = (_Float16)a0.y;
            a[2] = (_Float16)a0.z; a[3] = (_Float16)a0.w;
            a[4] = (_Float16)a1.x; a[5] = (_Float16)a1.y;
            a[6] = (_Float16)a1.z; a[7] = (_Float16)a1.w;

            const _Float16* wb = &Wt[r * LDK + kt * 32 + g * 8];
            half8 b0 = *(const half8*)(wb + 0 * 16 * LDK);
            half8 b1 = *(const half8*)(wb + 1 * 16 * LDK);
            half8 b2 = *(const half8*)(wb + 2 * 16 * LDK);
            half8 b3 = *(const half8*)(wb + 3 * 16 * LDK);
            acc0 = __builtin_amdgcn_mfma_f32_16x16x32_f16(a, b0, acc0, 0, 0, 0);
            acc1 = __builtin_amdgcn_mfma_f32_16x16x32_f16(a, b1, acc1, 0, 0, 0);
            acc2 = __builtin_amdgcn_mfma_f32_16x16x32_f16(a, b2, acc2, 0, 0, 0);
            acc3 = __builtin_amdgcn_mfma_f32_16x16x32_f16(a, b3, acc3, 0, 0, 0);
        }

        // D: col = lane&15 (=r), row = g*4 + j   [m89-verified]
#pragma unroll
        for (int j = 0; j < 4; ++j) {
            int drow = row0 + g * 4 + j;
            _Float16* o = h + (size_t)drow * 64 + r;
            if (drow < n) {
                o[0]  = (_Float16)acc0[j];
                o[16] = (_Float16)acc1[j];
                o[32] = (_Float16)acc2[j];
                o[48] = (_Float16)acc3[j];
            } else {                                   // sentinel zero rows [n, gb*64)
                o[0] = (_Float16)0; o[16] = (_Float16)0;
                o[32] = (_Float16)0; o[48] = (_Float16)0;
            }
        }
    } else {
        // ------------ partition ------------
        int* hist  = smem;
        int* bofs  = smem + 256;
        int* gbase = smem + 512;
        int* stage = smem + 768;                       // 4096 ints
        unsigned char* auxb = (unsigned char*)(smem + 4864);  // 4096 B
        const int tile0 = (blockIdx.x - gb) * P_TILE;
        const int tcnt  = min(P_TILE, E - tile0);

        hist[tid] = 0;
        __syncthreads();

        int pack[P_EPT], bb[P_EPT], lo[P_EPT];
#pragma unroll
        for (int i = 0; i < P_EPT; ++i) {
            int e = tile0 + i * 256 + tid;
            bb[i] = -1;
            if (e < E) {
                int d = dst[e];
                int s = src[e];
                bb[i]   = d >> BK_SHIFT;
                pack[i] = ((d & (BK_SIZE - 1)) << SRC_BITS) | s;
                lo[i]   = atomicAdd(&hist[bb[i]], 1);
            }
        }
        __syncthreads();

        bofs[tid] = hist[tid];
        __syncthreads();
        for (int off = 1; off < 256; off <<= 1) {
            int t = (tid >= off) ? bofs[tid - off] : 0;
            __syncthreads();
            bofs[tid] += t;
            __syncthreads();
        }
        int ex = bofs[tid] - hist[tid];
        __syncthreads();
        bofs[tid] = ex;                                // exclusive, for lookups
        if (hist[tid]) gbase[tid] = tid * CAP + atomicAdd(&bcur[tid], hist[tid]);
        __syncthreads();

#pragma unroll
        for (int i = 0; i < P_EPT; ++i) {
            if (bb[i] >= 0) {
                int p = bofs[bb[i]] + lo[i];
                stage[p] = pack[i];
                auxb[p]  = (unsigned char)bb[i];
            }
        }
        __syncthreads();

        for (int k = tid; k < tcnt; k += 256) {        // contiguous runs per bucket
            int b = auxb[k];
            part[gbase[b] + (k - bofs[b])] = stage[k];
        }
    }
}

// ---------------- per-bucket local fill (edge lists padded x4 with ZROW=n) ----------------

__global__ __launch_bounds__(256)
void bucket_fill_kernel(const int* __restrict__ bcur, const int* __restrict__ part,
                        int2* __restrict__ nodeinfo, float* __restrict__ dinv,
                        int* __restrict__ srcs, int n, int zrow) {
    __shared__ int cnt[BK_SIZE];
    __shared__ int rp[BK_SIZE];
    __shared__ int s2[256];
    __shared__ int total;
    const int tid   = threadIdx.x;
    const int bid   = blockIdx.x;
    const int node0 = bid << BK_SHIFT;
    const int bs    = min(BK_SIZE, n - node0);
    const int pbase = bid * CAP;
    const int sbase = bid * CAP2;
    const int ecnt  = bcur[bid];

    cnt[tid] = 0; cnt[tid + 256] = 0;
    __syncthreads();
    for (int k = tid; k < ecnt; k += 256)
        atomicAdd(&cnt[part[pbase + k] >> SRC_BITS], 1);
    __syncthreads();

    int c0 = cnt[2 * tid], c1 = cnt[2 * tid + 1];
    int p0 = (c0 + 3) & ~3, p1 = (c1 + 3) & ~3;           // padded counts
    s2[tid] = p0 + p1;
    __syncthreads();
    for (int off = 1; off < 256; off <<= 1) {
        int t = (tid >= off) ? s2[tid - off] : 0;
        __syncthreads();
        s2[tid] += t;
        __syncthreads();
    }
    int ex = s2[tid] - (p0 + p1);
    rp[2 * tid]     = ex;
    rp[2 * tid + 1] = ex + p0;
    if (tid == 255) total = s2[255];
    __syncthreads();

    for (int i = tid; i < bs; i += 256) {                  // coalesced
        int c = cnt[i];
        nodeinfo[node0 + i] = make_int2(sbase + rp[i], (c + 3) & ~3);
        dinv[node0 + i]     = rsqrtf((float)c + 1.0f);     // +1 self-loop
    }
    __syncthreads();

    cnt[tid] = 0; cnt[tid + 256] = 0;                      // reuse as cursors
    __syncthreads();
    for (int k = tid; k < total; k += 256) srcs[sbase + k] = zrow;  // pad fill
    __syncthreads();
    for (int k = tid; k < ecnt; k += 256) {
        int v    = part[pbase + k];
        int li   = v >> SRC_BITS;
        int slot = atomicAdd(&cnt[li], 1);
        srcs[sbase + rp[li] + slot] = v & ((1 << SRC_BITS) - 1);  // L2-local window
    }
}

// ---------------- fused B: gather layer-1 + relu into LDS tile, then MFMA with W2 ----------------
// 64 sequential nodes/block. h2 written PRE-SCALED by dinv[row] (coalesced rows;
// rows >= n get 0 -> h2 sentinel row n is zero for free).

__global__ __launch_bounds__(256)
void layer2_fused_kernel(const int2* __restrict__ nodeinfo, const int* __restrict__ srcs,
                         const float* __restrict__ dinv, const half8* __restrict__ hs,
                         const float* __restrict__ b1, const float* __restrict__ W2,
                         _Float16* __restrict__ h2, int n) {
    __shared__ _Float16 At[64 * 72];
    __shared__ _Float16 Wt[64 * 72];
    const int tid = threadIdx.x;

    for (int idx = tid; idx < 64 * 64; idx += 256) {   // W2[k][c] -> Wt[c][k] fp16
        int k = idx >> 6, c = idx & 63;
        Wt[c * 72 + k] = (_Float16)W2[idx];
    }

    const int f    = tid & 7;
    const int grp  = tid >> 3;
    const int row0 = blockIdx.x * 64;

#pragma unroll
    for (int rnd = 0; rnd < 2; ++rnd) {
        const int nrow = rnd * 32 + grp;
        const int node = row0 + nrow;
        half8 o = {};
        if (node < n) {
            int2 info = nodeinfo[node];
            int start = info.x, cpad = info.y;
            float dn = dinv[node];
            half8 sv = hs[(size_t)node * 8 + f];       // self-loop term
            float acc[8];
#pragma unroll
            for (int i = 0; i < 8; ++i) acc[i] = dn * (float)sv[i];

            if (cpad > 0) {
                int4 ss = *(const int4*)&srcs[start];  // pipelined srcs prefetch
                for (int j = 0; j < cpad; j += 4) {
                    int4 nxt = *(const int4*)&srcs[start + j + 4];  // over-read lands in ws
                    float d0 = dinv[ss.x], d1 = dinv[ss.y], d2 = dinv[ss.z], d3 = dinv[ss.w];
                    half8 v0 = hs[(size_t)ss.x * 8 + f];
                    half8 v1 = hs[(size_t)ss.y * 8 + f];
                    half8 v2 = hs[(size_t)ss.z * 8 + f];
                    half8 v3 = hs[(size_t)ss.w * 8 + f];
#pragma unroll
                    for (int i = 0; i < 8; ++i)
                        acc[i] += (d0 * (float)v0[i] + d1 * (float)v1[i]) +
                                  (d2 * (float)v2[i] + d3 * (float)v3[i]);
                    ss = nxt;
                }
            }
#pragma unroll
            for (int i = 0; i < 8; ++i) {
                float g1 = fmaf(acc[i], dn, b1[f * 8 + i]);
                o[i] = (_Float16)fmaxf(g1, 0.0f);      // relu
            }
        }
        *(half8*)&At[nrow * 72 + f * 8] = o;
    }
    __syncthreads();

    // MFMA phase: wave w -> 16 output rows, K=64
    const int wave = tid >> 6;
    const int lane = tid & 63;
    const int r    = lane & 15;
    const int g    = lane >> 4;

    floatx4 acc0 = {}, acc1 = {}, acc2 = {}, acc3 = {};
#pragma unroll
    for (int kt = 0; kt < 2; ++kt) {
        half8 a = *(const half8*)&At[(wave * 16 + r) * 72 + kt * 32 + g * 8];
        const _Float16* wb = &Wt[r * 72 + kt * 32 + g * 8];
        half8 b0 = *(const half8*)(wb + 0 * 16 * 72);
        half8 b1v = *(const half8*)(wb + 1 * 16 * 72);
        half8 b2v = *(const half8*)(wb + 2 * 16 * 72);
        half8 b3v = *(const half8*)(wb + 3 * 16 * 72);
        acc0 = __builtin_amdgcn_mfma_f32_16x16x32_f16(a, b0, acc0, 0, 0, 0);
        acc1 = __builtin_amdgcn_mfma_f32_16x16x32_f16(a, b1v, acc1, 0, 0, 0);
        acc2 = __builtin_amdgcn_mfma_f32_16x16x32_f16(a, b2v, acc2, 0, 0, 0);
        acc3 = __builtin_amdgcn_mfma_f32_16x16x32_f16(a, b3v, acc3, 0, 0, 0);
    }

    // D: col = r, row = wave*16 + g*4 + j; store PRE-SCALED (sequential, coalesced)
#pragma unroll
    for (int j = 0; j < 4; ++j) {
        int drow = row0 + wave * 16 + g * 4 + j;
        float dn2 = (drow < n) ? dinv[drow] : 0.0f;    // rows >= n -> 0 (incl. row n sentinel)
        _Float16* o = h2 + (size_t)drow * 64 + r;
        o[0]  = (_Float16)(acc0[j] * dn2);
        o[16] = (_Float16)(acc1[j] * dn2);
        o[32] = (_Float16)(acc2[j] * dn2);
        o[48] = (_Float16)(acc3[j] * dn2);
    }
}

// ---------------- final gather: out[d] = dinv[d]*(sum h2[s] + h2[d]) + b2 ----------------
// h2 pre-scaled by dinv -> NO per-edge dinv loads. Sequential node order (coalesced).

__global__ __launch_bounds__(256)
void gather_out_kernel(const int2* __restrict__ nodeinfo, const int* __restrict__ srcs,
                       const float* __restrict__ dinv, const half8* __restrict__ hs,
                       const float* __restrict__ b, float* __restrict__ out, int n) {
    const int tid  = threadIdx.x;
    const int f    = tid & 7;
    const int node = blockIdx.x * 32 + (tid >> 3);
    if (node >= n) return;

    int2 info = nodeinfo[node];
    int start = info.x, cpad = info.y;

    half8 sv = hs[(size_t)node * 8 + f];   // self term (pre-scaled)
    float acc[8];
#pragma unroll
    for (int i = 0; i < 8; ++i) acc[i] = (float)sv[i];

    if (cpad > 0) {
        int4 ss = *(const int4*)&srcs[start];          // pipelined srcs prefetch
        for (int j = 0; j < cpad; j += 4) {
            int4 nxt = *(const int4*)&srcs[start + j + 4];  // over-read lands in ws
            half8 v0 = hs[(size_t)ss.x * 8 + f];
            half8 v1 = hs[(size_t)ss.y * 8 + f];
            half8 v2 = hs[(size_t)ss.z * 8 + f];
            half8 v3 = hs[(size_t)ss.w * 8 + f];
#pragma unroll
            for (int i = 0; i < 8; ++i)
                acc[i] += ((float)v0[i] + (float)v1[i]) + ((float)v2[i] + (float)v3[i]);
            ss = nxt;
        }
    }

    float dn = dinv[node];
    const float4* b4 = (const float4*)b;
    float4 bb0 = b4[f * 2], bb1 = b4[f * 2 + 1];
    float4 o0 = make_float4(fmaf(acc[0], dn, bb0.x), fmaf(acc[1], dn, bb0.y),
                            fmaf(acc[2], dn, bb0.z), fmaf(acc[3], dn, bb0.w));
    float4 o1 = make_float4(fmaf(acc[4], dn, bb1.x), fmaf(acc[5], dn, bb1.y),
                            fmaf(acc[6], dn, bb1.z), fmaf(acc[7], dn, bb1.w));
    float4* o4 = (float4*)out;
    o4[(size_t)node * 16 + f * 2]     = o0;
    o4[(size_t)node * 16 + f * 2 + 1] = o1;
}

// ---------------- launch ----------------

extern "C" void kernel_launch(void* const* d_in, const int* in_sizes, int n_in,
                              void* d_out, int out_size, void* d_ws, size_t ws_size,
                              hipStream_t stream) {
    const float* x   = (const float*)d_in[0];
    const int*   ei  = (const int*)d_in[1];   // int64 demoted to int32 by JAX default config
    const float* W1  = (const float*)d_in[2];
    const float* b1  = (const float*)d_in[3];
    const float* W2  = (const float*)d_in[4];
    const float* b2  = (const float*)d_in[5];
    float*       out = (float*)d_out;

    const int n = in_sizes[0] / DIM_IN;   // 100000
    const int E = in_sizes[1] / 2;        // 1000000
    const int* srcp = ei;
    const int* dstp = ei + E;
    const int NB    = (n + BK_SIZE - 1) >> BK_SHIFT;   // 196
    const int gb    = (n + 63) / 64;                   // 1563
    const int pb    = (E + P_TILE - 1) / P_TILE;       // 245
    const int ab    = (n + 31) / 32;
    const size_t nrows = (size_t)gb * 64;              // h rows incl. zero sentinels

    const int npad = ((n + 255) / 256) * 256;

    // workspace layout (4B words):
    int*      bcur     = (int*)d_ws;                          // 256
    int2*     nodeinfo = (int2*)(bcur + 256);                 // 2*npad words
    float*    dinv     = (float*)((int*)nodeinfo + 2 * npad); // npad (incl. dinv[n] sentinel)
    int*      srcs     = (int*)(dinv + npad);                 // NB*CAP2
    int*      part     = srcs + (size_t)NB * CAP2;            // NB*CAP
    _Float16* h        = (_Float16*)(part + (size_t)NB * CAP); // nrows*64 halves
    _Float16* h2       = h + nrows * 64;                      // nrows*64 halves (rows >= n zero)

    // 1) init cursors + sentinel dinv
    zero_kernel<<<1, 256, 0, stream>>>(bcur, &dinv[n]);
    // 2) gemm1 (h = fp16(x@W1), raw) overlapped with edge partition
    gemm1_partition_kernel<<<gb + pb, 256, 0, stream>>>(x, W1, h, n, gb,
                                                        srcp, dstp, bcur, part, E);
    // 3) per-bucket CSR fill (nodeinfo, dinv, padded srcs)
    bucket_fill_kernel<<<NB, 256, 0, stream>>>(bcur, part, nodeinfo, dinv, srcs, n, n);
    // 4) layer1 gather + relu + layer2 GEMM fused -> h2 (pre-scaled by dinv)
    layer2_fused_kernel<<<gb, 256, 0, stream>>>(nodeinfo, srcs, dinv, (const half8*)h,
                                                b1, W2, h2, n);
    // 5) layer2 gather -> out (fp32)
    gather_out_kernel<<<ab, 256, 0, stream>>>(nodeinfo, srcs, dinv, (const half8*)h2,
                                              b2, out, n);
}